// Round 2
// baseline (3396.063 us; speedup 1.0000x reference)
//
#include <hip/hip_runtime.h>
#include <hip/hip_bf16.h>
#include <stdint.h>

#define E_DIM 1280
#define F_DIM 5120
#define T_DIM 16384
#define B_SZ  16
#define S_LEN 1024
#define NH    20

typedef int v4i __attribute__((ext_vector_type(4)));

// ---------- helpers ----------
__device__ __forceinline__ float wred_sum(float v) {
#pragma unroll
  for (int m = 32; m > 0; m >>= 1) v += __shfl_xor(v, m, 64);
  return v;
}
__device__ __forceinline__ float wred_max(float v) {
#pragma unroll
  for (int m = 32; m > 0; m >>= 1) v = fmaxf(v, __shfl_xor(v, m, 64));
  return v;
}
__device__ __forceinline__ float bf_lo(unsigned u) {
  union { unsigned i; float f; } x; x.i = u << 16; return x.f;
}
__device__ __forceinline__ float bf_hi(unsigned u) {
  union { unsigned i; float f; } x; x.i = u & 0xffff0000u; return x.f;
}
__device__ __forceinline__ void gload_lds16(const void* g, void* l) {
  __builtin_amdgcn_global_load_lds((const __attribute__((address_space(1))) void*)g,
                                   (__attribute__((address_space(3))) void*)l, 16, 0, 0);
}

// ---------- per-output-channel weight quant ----------
__global__ __launch_bounds__(256) void wquant_kernel(
    const float* __restrict__ W, int8_t* __restrict__ qw, float* __restrict__ sw, int K) {
  __shared__ float red[4];
  const int row = blockIdx.x;
  const int tid = threadIdx.x;
  const float* wr = W + (size_t)row * K;
  float amax = 0.f;
  for (int c = tid; c < K; c += 256) amax = fmaxf(amax, fabsf(wr[c]));
  amax = wred_max(amax);
  if ((tid & 63) == 0) red[tid >> 6] = amax;
  __syncthreads();
  amax = fmaxf(fmaxf(red[0], red[1]), fmaxf(red[2], red[3]));
  float sc = amax * (1.0f / 127.0f);
  if (tid == 0) sw[row] = sc;
  for (int c = tid; c < K; c += 256) {
    float qv = rintf(wr[c] / sc);
    qw[(size_t)row * K + c] = (int8_t)qv;
  }
}

// ---------- RMSNorm(+bias) + per-token quant (E=1280) ----------
__global__ __launch_bounds__(256) void rms_quant_kernel(
    const float* __restrict__ x, const float* __restrict__ w, const float* __restrict__ b,
    int8_t* __restrict__ q, float* __restrict__ s) {
  __shared__ float red[4];
  const int row = blockIdx.x;
  const int tid = threadIdx.x;
  const float* xr = x + (size_t)row * E_DIM;
  float vals[5];
  float ss = 0.f;
#pragma unroll
  for (int i = 0; i < 5; ++i) {
    float v = xr[tid + i * 256];
    vals[i] = v; ss += v * v;
  }
  ss = wred_sum(ss);
  if ((tid & 63) == 0) red[tid >> 6] = ss;
  __syncthreads();
  ss = red[0] + red[1] + red[2] + red[3];
  float rstd = rsqrtf(ss * (1.0f / E_DIM) + 1e-6f);
  float y[5]; float amax = 0.f;
#pragma unroll
  for (int i = 0; i < 5; ++i) {
    int c = tid + i * 256;
    float v = vals[i] * rstd * w[c] + b[c];
    y[i] = v;
    amax = fmaxf(amax, fabsf(v));
  }
  amax = wred_max(amax);
  __syncthreads();
  if ((tid & 63) == 0) red[tid >> 6] = amax;
  __syncthreads();
  amax = fmaxf(fmaxf(red[0], red[1]), fmaxf(red[2], red[3]));
  float sc = amax * (1.0f / 127.0f);
  if (tid == 0) s[row] = sc;
#pragma unroll
  for (int i = 0; i < 5; ++i) {
    int c = tid + i * 256;
    float qv = rintf(y[i] / sc);
    qv = fminf(fmaxf(qv, -127.f), 127.f);
    q[(size_t)row * E_DIM + c] = (int8_t)qv;
  }
}

// ---------- plain per-token quant (E=1280, fp32 in) ----------
__global__ __launch_bounds__(256) void row_quant_kernel(
    const float* __restrict__ x, int8_t* __restrict__ q, float* __restrict__ s) {
  __shared__ float red[4];
  const int row = blockIdx.x;
  const int tid = threadIdx.x;
  const float* xr = x + (size_t)row * E_DIM;
  float vals[5]; float amax = 0.f;
#pragma unroll
  for (int i = 0; i < 5; ++i) {
    float v = xr[tid + i * 256];
    vals[i] = v;
    amax = fmaxf(amax, fabsf(v));
  }
  amax = wred_max(amax);
  if ((tid & 63) == 0) red[tid >> 6] = amax;
  __syncthreads();
  amax = fmaxf(fmaxf(red[0], red[1]), fmaxf(red[2], red[3]));
  float sc = amax * (1.0f / 127.0f);
  if (tid == 0) s[row] = sc;
#pragma unroll
  for (int i = 0; i < 5; ++i) {
    int c = tid + i * 256;
    float qv = rintf(vals[i] / sc);
    qv = fminf(fmaxf(qv, -127.f), 127.f);
    q[(size_t)row * E_DIM + c] = (int8_t)qv;
  }
}

// ---------- exact GELU + per-token quant (F=5120, bf16 in) ----------
// q is written IN-PLACE into the f1 buffer: row stride 2*F bytes (first F bytes
// of each bf16 row). All reads of the row complete before the amax-reduction
// barriers; writes happen after -> race-free.
__global__ __launch_bounds__(256) void gelu_quant_kernel(
    const __hip_bfloat16* __restrict__ f1, int8_t* __restrict__ q, float* __restrict__ s) {
  __shared__ float red[4];
  const int row = blockIdx.x;
  const int tid = threadIdx.x;
  const __hip_bfloat16* xr = f1 + (size_t)row * F_DIM;
  float g[20]; float amax = 0.f;
#pragma unroll
  for (int i = 0; i < 20; ++i) {
    float v = __bfloat162float(xr[tid + i * 256]);
    float gv = 0.5f * v * (1.0f + erff(v * 0.70710678118654752440f));
    g[i] = gv;
    amax = fmaxf(amax, fabsf(gv));
  }
  amax = wred_max(amax);
  if ((tid & 63) == 0) red[tid >> 6] = amax;
  __syncthreads();
  amax = fmaxf(fmaxf(red[0], red[1]), fmaxf(red[2], red[3]));
  float sc = amax * (1.0f / 127.0f);
  if (tid == 0) s[row] = sc;
  int8_t* qr = q + (size_t)row * (2 * F_DIM);   // strided in-place rows
#pragma unroll
  for (int i = 0; i < 20; ++i) {
    int c = tid + i * 256;
    float qv = rintf(g[i] / sc);
    qv = fminf(fmaxf(qv, -127.f), 127.f);
    qr[c] = (int8_t)qv;
  }
}

// ---------- int8 GEMM: C[m,n] = sum_k A[m,k]*B[n,k]; dequant epilogue ----------
// MODE 0: out bf16 = acc*sx*sw + bias           (QKV, FC1)
// MODE 1: out f32  = acc*sx*sw + bias + resid   (Out-proj, FC2; resid may alias out)
template <int MODE>
__global__ __launch_bounds__(256) void gemm_i8(
    const int8_t* __restrict__ A, const int8_t* __restrict__ B,
    const float* __restrict__ sx, const float* __restrict__ sw,
    const float* __restrict__ bias, const float* __restrict__ resid,
    void* __restrict__ outp, int M, int N, int K, int lda) {
  __shared__ __align__(16) int8_t Asl[128 * 64];
  __shared__ __align__(16) int8_t Bsl[128 * 64];
  const int tid = threadIdx.x;
  const int lane = tid & 63;
  const int wave = tid >> 6;
  const int wm = wave >> 1, wn = wave & 1;
  const int quad = lane >> 4;
  const int l16 = lane & 15;
  const int m0 = blockIdx.y * 128;
  const int n0 = blockIdx.x * 128;

  v4i acc[4][4];
#pragma unroll
  for (int i = 0; i < 4; ++i)
#pragma unroll
    for (int j = 0; j < 4; ++j) acc[i][j] = (v4i){0, 0, 0, 0};

  const int nk = K >> 6;
#pragma unroll 1
  for (int ks = 0; ks < nk; ++ks) {
    __syncthreads();  // previous compute done before LDS overwrite
    const long k0 = (long)ks * 64;
#pragma unroll
    for (int issue = 0; issue < 2; ++issue) {
      int c = (issue * 4 + wave) * 64 + lane;     // chunk index; LDS offset = c*16
      int row = c >> 2;
      int scol = (c & 3) << 4;
      int gcol = scol ^ ((row & 3) << 4);         // XOR swizzle
      gload_lds16(A + (long)(m0 + row) * lda + k0 + gcol, &Asl[c * 16]);
      gload_lds16(B + (long)(n0 + row) * K + k0 + gcol, &Bsl[c * 16]);
    }
    __syncthreads();  // vmcnt(0) drain before reads
    v4i af[4], bf[4];
#pragma unroll
    for (int i = 0; i < 4; ++i) {
      int row = wm * 64 + i * 16 + l16;
      af[i] = *(const v4i*)&Asl[row * 64 + ((quad * 16) ^ ((row & 3) << 4))];
    }
#pragma unroll
    for (int j = 0; j < 4; ++j) {
      int row = wn * 64 + j * 16 + l16;
      bf[j] = *(const v4i*)&Bsl[row * 64 + ((quad * 16) ^ ((row & 3) << 4))];
    }
#pragma unroll
    for (int i = 0; i < 4; ++i)
#pragma unroll
      for (int j = 0; j < 4; ++j)
        acc[i][j] = __builtin_amdgcn_mfma_i32_16x16x64_i8(af[i], bf[j], acc[i][j], 0, 0, 0);
  }

  // epilogue: C row = quad*4 + r, col = l16 within each 16x16 tile
  float swv[4], bv[4];
#pragma unroll
  for (int j = 0; j < 4; ++j) {
    int n = n0 + wn * 64 + j * 16 + l16;
    swv[j] = sw[n];
    bv[j] = bias[n];
  }
#pragma unroll
  for (int i = 0; i < 4; ++i) {
#pragma unroll
    for (int r = 0; r < 4; ++r) {
      int m = m0 + wm * 64 + i * 16 + quad * 4 + r;
      float sxm = sx[m];
#pragma unroll
      for (int j = 0; j < 4; ++j) {
        int n = n0 + wn * 64 + j * 16 + l16;
        float v = (float)acc[i][j][r] * (sxm * swv[j]) + bv[j];
        if constexpr (MODE == 0) {
          ((__hip_bfloat16*)outp)[(size_t)m * N + n] = __float2bfloat16(v);
        } else {
          ((float*)outp)[(size_t)m * N + n] = v + resid[(size_t)m * N + n];
        }
      }
    }
  }
}

// ---------- attention: per (b,h,8-q-row strip); exact softmax; fp32 VALU ----------
__global__ __launch_bounds__(256) void attn_kernel(
    const __hip_bfloat16* __restrict__ qkv, float* __restrict__ attn) {
  const int E3 = 3 * E_DIM;  // 3840
  __shared__ float Qs[8][64];
  __shared__ float sc[8][1028];
  __shared__ float red2[4][8][64];
  const int tid = threadIdx.x;
  const int lane = tid & 63;
  const int wave = tid >> 6;
  const int bh = blockIdx.y;
  const int b = bh / NH, h = bh % NH;
  const int q0 = blockIdx.x * 8;
  const size_t base_t = (size_t)b * S_LEN;

  // load Q strip (scaled by 1/sqrt(hd)=0.125)
  const __hip_bfloat16* qbase = qkv + (base_t + q0) * E3 + h * 64;
  for (int i = tid; i < 8 * 64; i += 256) {
    int r = i >> 6, d = i & 63;
    Qs[r][d] = __bfloat162float(qbase[(size_t)r * E3 + d]) * 0.125f;
  }
  __syncthreads();

  // ---- scores: thread handles k = tid + j*256, j=0..3 ----
  {
    const __hip_bfloat16* k0p = qkv + base_t * E3 + E_DIM + h * 64 + (size_t)tid * E3;
    float acc[8][4];
#pragma unroll
    for (int qq = 0; qq < 8; ++qq)
#pragma unroll
      for (int j = 0; j < 4; ++j) acc[qq][j] = 0.f;
#pragma unroll 1
    for (int c = 0; c < 8; ++c) {
      uint4 kw[4];
#pragma unroll
      for (int j = 0; j < 4; ++j)
        kw[j] = *(const uint4*)(k0p + (size_t)j * 256 * E3 + c * 8);
#pragma unroll
      for (int p = 0; p < 4; ++p) {
        int d = c * 8 + p * 2;
        float k0v[4], k1v[4];
#pragma unroll
        for (int j = 0; j < 4; ++j) {
          unsigned u = ((const unsigned*)&kw[j])[p];
          k0v[j] = bf_lo(u); k1v[j] = bf_hi(u);
        }
#pragma unroll
        for (int qq = 0; qq < 8; ++qq) {
          float qa = Qs[qq][d], qb = Qs[qq][d + 1];
#pragma unroll
          for (int j = 0; j < 4; ++j)
            acc[qq][j] = fmaf(k1v[j], qb, fmaf(k0v[j], qa, acc[qq][j]));
        }
      }
    }
#pragma unroll
    for (int qq = 0; qq < 8; ++qq)
#pragma unroll
      for (int j = 0; j < 4; ++j) sc[qq][tid + j * 256] = acc[qq][j];
  }
  __syncthreads();

  // ---- softmax: wave handles 2 rows ----
#pragma unroll 1
  for (int rr = 0; rr < 2; ++rr) {
    int r = wave * 2 + rr;
    float m = -1e30f;
#pragma unroll
    for (int j = 0; j < 16; ++j) m = fmaxf(m, sc[r][lane + j * 64]);
    m = wred_max(m);
    float sum = 0.f;
#pragma unroll
    for (int j = 0; j < 16; ++j) {
      float e = __expf(sc[r][lane + j * 64] - m);
      sc[r][lane + j * 64] = e;
      sum += e;
    }
    sum = wred_sum(sum);
    float inv = 1.0f / sum;
#pragma unroll
    for (int j = 0; j < 16; ++j) sc[r][lane + j * 64] *= inv;
  }
  __syncthreads();

  // ---- PV: wave w covers k in [w*256, w*256+256), all 8 rows, lane = d ----
  {
    const __hip_bfloat16* vb = qkv + base_t * E3 + 2 * E_DIM + h * 64 + lane;
    float acc[8];
#pragma unroll
    for (int r = 0; r < 8; ++r) acc[r] = 0.f;
#pragma unroll 2
    for (int kk = 0; kk < 64; ++kk) {
      int k = wave * 256 + kk * 4;
      float vv[4];
#pragma unroll
      for (int u = 0; u < 4; ++u) vv[u] = __bfloat162float(vb[(size_t)(k + u) * E3]);
#pragma unroll
      for (int r = 0; r < 8; ++r) {
        float4 p = *(const float4*)&sc[r][k];  // broadcast b128
        acc[r] = fmaf(p.w, vv[3], fmaf(p.z, vv[2], fmaf(p.y, vv[1], fmaf(p.x, vv[0], acc[r]))));
      }
    }
#pragma unroll
    for (int r = 0; r < 8; ++r) red2[wave][r][lane] = acc[r];
  }
  __syncthreads();
  for (int o = tid; o < 8 * 64; o += 256) {
    int r = o >> 6, d = o & 63;
    float v = red2[0][r][d] + red2[1][r][d] + red2[2][r][d] + red2[3][r][d];
    attn[(base_t + q0 + r) * (size_t)E_DIM + h * 64 + d] = v;
  }
}

// ---------- launch ----------
extern "C" void kernel_launch(void* const* d_in, const int* in_sizes, int n_in,
                              void* d_out, int out_size, void* d_ws, size_t ws_size,
                              hipStream_t stream) {
  const float* hidden = (const float*)d_in[0];
  const float* ln1_w = (const float*)d_in[1];
  const float* ln1_b = (const float*)d_in[2];
  const float* ln2_w = (const float*)d_in[3];
  const float* ln2_b = (const float*)d_in[4];
  const float* W_qkv = (const float*)d_in[5];
  const float* b_qkv = (const float*)d_in[6];
  const float* W_out = (const float*)d_in[7];
  const float* b_out = (const float*)d_in[8];
  const float* W_fc1 = (const float*)d_in[9];
  const float* b_fc1 = (const float*)d_in[10];
  const float* W_fc2 = (const float*)d_in[11];
  const float* b_fc2 = (const float*)d_in[12];

  // ---- workspace plan (total ~250.7 MB) ----
  char* ws = (char*)d_ws;
  size_t off = 0;
  auto alloc = [&](size_t bytes) {
    void* p = ws + off;
    off += (bytes + 255) & ~(size_t)255;
    return p;
  };
  int8_t* qw_qkv = (int8_t*)alloc((size_t)3 * E_DIM * E_DIM);
  int8_t* qw_out = (int8_t*)alloc((size_t)E_DIM * E_DIM);
  int8_t* qw_fc1 = (int8_t*)alloc((size_t)F_DIM * E_DIM);
  int8_t* qw_fc2 = (int8_t*)alloc((size_t)E_DIM * F_DIM);
  float* sw_qkv = (float*)alloc((size_t)3 * E_DIM * 4);
  float* sw_out = (float*)alloc((size_t)E_DIM * 4);
  float* sw_fc1 = (float*)alloc((size_t)F_DIM * 4);
  float* sw_fc2 = (float*)alloc((size_t)E_DIM * 4);
  float* sx1 = (float*)alloc((size_t)T_DIM * 4);
  float* sa  = (float*)alloc((size_t)T_DIM * 4);
  float* sx2 = (float*)alloc((size_t)T_DIM * 4);
  float* sg  = (float*)alloc((size_t)T_DIM * 4);
  int8_t* qx = (int8_t*)alloc((size_t)T_DIM * E_DIM);              // reused 3x
  char* R = (char*)alloc((size_t)T_DIM * 3 * E_DIM * 2 +           // qkv bf16 (126MB)
                         (size_t)T_DIM * E_DIM * 4);               // attn f32 (84MB)
  // phase A aliases
  __hip_bfloat16* qkv_bf = (__hip_bfloat16*)R;
  float* attn_f = (float*)(R + (size_t)T_DIM * 3 * E_DIM * 2);
  // phase B aliases (qkv/attn dead by then)
  __hip_bfloat16* f1_bf = (__hip_bfloat16*)R;                      // 168MB <= 210MB
  int8_t* qg = (int8_t*)R;                                         // strided lda=2F
  // hidden2 lives in d_out (fully overwritten by out-proj before any read)
  float* hidden2 = (float*)d_out;

  // 1) weight quantization
  wquant_kernel<<<3 * E_DIM, 256, 0, stream>>>(W_qkv, qw_qkv, sw_qkv, E_DIM);
  wquant_kernel<<<E_DIM, 256, 0, stream>>>(W_out, qw_out, sw_out, E_DIM);
  wquant_kernel<<<F_DIM, 256, 0, stream>>>(W_fc1, qw_fc1, sw_fc1, E_DIM);
  wquant_kernel<<<E_DIM, 256, 0, stream>>>(W_fc2, qw_fc2, sw_fc2, F_DIM);
  // 2) rms1 + quant
  rms_quant_kernel<<<T_DIM, 256, 0, stream>>>(hidden, ln1_w, ln1_b, qx, sx1);
  // 3) QKV gemm -> bf16
  gemm_i8<0><<<dim3(3 * E_DIM / 128, T_DIM / 128), 256, 0, stream>>>(
      qx, qw_qkv, sx1, sw_qkv, b_qkv, nullptr, qkv_bf, T_DIM, 3 * E_DIM, E_DIM, E_DIM);
  // 4) attention
  attn_kernel<<<dim3(S_LEN / 8, B_SZ * NH), 256, 0, stream>>>(qkv_bf, attn_f);
  // 5) quant attn
  row_quant_kernel<<<T_DIM, 256, 0, stream>>>(attn_f, qx, sa);
  // 6) out proj + residual -> hidden2 (= d_out)
  gemm_i8<1><<<dim3(E_DIM / 128, T_DIM / 128), 256, 0, stream>>>(
      qx, qw_out, sa, sw_out, b_out, hidden, hidden2, T_DIM, E_DIM, E_DIM, E_DIM);
  // 7) rms2 + quant
  rms_quant_kernel<<<T_DIM, 256, 0, stream>>>(hidden2, ln2_w, ln2_b, qx, sx2);
  // 8) FC1 gemm -> bf16 (R region free again)
  gemm_i8<0><<<dim3(F_DIM / 128, T_DIM / 128), 256, 0, stream>>>(
      qx, qw_fc1, sx2, sw_fc1, b_fc1, nullptr, f1_bf, T_DIM, F_DIM, E_DIM, E_DIM);
  // 9) gelu + quant (in-place strided int8 rows inside f1 buffer)
  gelu_quant_kernel<<<T_DIM, 256, 0, stream>>>(f1_bf, qg, sg);
  // 10) FC2 gemm + residual -> d_out (in-place read-modify-write, element-private)
  gemm_i8<1><<<dim3(E_DIM / 128, T_DIM / 128), 256, 0, stream>>>(
      qg, qw_fc2, sg, sw_fc2, b_fc2, hidden2, (float*)d_out, T_DIM, E_DIM, F_DIM, 2 * F_DIM);
}

// Round 3
// 1590.098 us; speedup vs baseline: 2.1358x; 2.1358x over previous
//
#include <hip/hip_runtime.h>
#include <hip/hip_bf16.h>
#include <stdint.h>

#define E_DIM 1280
#define F_DIM 5120
#define T_DIM 16384
#define B_SZ  16
#define S_LEN 1024
#define NH    20

typedef int v4i __attribute__((ext_vector_type(4)));
typedef __attribute__((ext_vector_type(8))) short v8s;
typedef __attribute__((ext_vector_type(4))) float v4f;

// ---------- helpers ----------
__device__ __forceinline__ float wred_sum(float v) {
#pragma unroll
  for (int m = 32; m > 0; m >>= 1) v += __shfl_xor(v, m, 64);
  return v;
}
__device__ __forceinline__ float wred_max(float v) {
#pragma unroll
  for (int m = 32; m > 0; m >>= 1) v = fmaxf(v, __shfl_xor(v, m, 64));
  return v;
}
__device__ __forceinline__ void gload_lds16(const void* g, void* l) {
  __builtin_amdgcn_global_load_lds((const __attribute__((address_space(1))) void*)g,
                                   (__attribute__((address_space(3))) void*)l, 16, 0, 0);
}

// ---------- per-output-channel weight quant ----------
__global__ __launch_bounds__(256) void wquant_kernel(
    const float* __restrict__ W, int8_t* __restrict__ qw, float* __restrict__ sw, int K) {
  __shared__ float red[4];
  const int row = blockIdx.x;
  const int tid = threadIdx.x;
  const float* wr = W + (size_t)row * K;
  float amax = 0.f;
  for (int c = tid; c < K; c += 256) amax = fmaxf(amax, fabsf(wr[c]));
  amax = wred_max(amax);
  if ((tid & 63) == 0) red[tid >> 6] = amax;
  __syncthreads();
  amax = fmaxf(fmaxf(red[0], red[1]), fmaxf(red[2], red[3]));
  float sc = amax * (1.0f / 127.0f);
  if (tid == 0) sw[row] = sc;
  for (int c = tid; c < K; c += 256) {
    float qv = rintf(wr[c] / sc);
    qw[(size_t)row * K + c] = (int8_t)qv;
  }
}

// ---------- RMSNorm(+bias) + per-token quant (E=1280) ----------
__global__ __launch_bounds__(256) void rms_quant_kernel(
    const float* __restrict__ x, const float* __restrict__ w, const float* __restrict__ b,
    int8_t* __restrict__ q, float* __restrict__ s) {
  __shared__ float red[4];
  const int row = blockIdx.x;
  const int tid = threadIdx.x;
  const float* xr = x + (size_t)row * E_DIM;
  float vals[5];
  float ss = 0.f;
#pragma unroll
  for (int i = 0; i < 5; ++i) {
    float v = xr[tid + i * 256];
    vals[i] = v; ss += v * v;
  }
  ss = wred_sum(ss);
  if ((tid & 63) == 0) red[tid >> 6] = ss;
  __syncthreads();
  ss = red[0] + red[1] + red[2] + red[3];
  float rstd = rsqrtf(ss * (1.0f / E_DIM) + 1e-6f);
  float y[5]; float amax = 0.f;
#pragma unroll
  for (int i = 0; i < 5; ++i) {
    int c = tid + i * 256;
    float v = vals[i] * rstd * w[c] + b[c];
    y[i] = v;
    amax = fmaxf(amax, fabsf(v));
  }
  amax = wred_max(amax);
  __syncthreads();
  if ((tid & 63) == 0) red[tid >> 6] = amax;
  __syncthreads();
  amax = fmaxf(fmaxf(red[0], red[1]), fmaxf(red[2], red[3]));
  float sc = amax * (1.0f / 127.0f);
  if (tid == 0) s[row] = sc;
#pragma unroll
  for (int i = 0; i < 5; ++i) {
    int c = tid + i * 256;
    float qv = rintf(y[i] / sc);
    qv = fminf(fmaxf(qv, -127.f), 127.f);
    q[(size_t)row * E_DIM + c] = (int8_t)qv;
  }
}

// ---------- per-token quant (E=1280, bf16 in) ----------
__global__ __launch_bounds__(256) void row_quant_bf_kernel(
    const __hip_bfloat16* __restrict__ x, int8_t* __restrict__ q, float* __restrict__ s) {
  __shared__ float red[4];
  const int row = blockIdx.x;
  const int tid = threadIdx.x;
  const __hip_bfloat16* xr = x + (size_t)row * E_DIM;
  float vals[5]; float amax = 0.f;
#pragma unroll
  for (int i = 0; i < 5; ++i) {
    float v = __bfloat162float(xr[tid + i * 256]);
    vals[i] = v;
    amax = fmaxf(amax, fabsf(v));
  }
  amax = wred_max(amax);
  if ((tid & 63) == 0) red[tid >> 6] = amax;
  __syncthreads();
  amax = fmaxf(fmaxf(red[0], red[1]), fmaxf(red[2], red[3]));
  float sc = amax * (1.0f / 127.0f);
  if (tid == 0) s[row] = sc;
#pragma unroll
  for (int i = 0; i < 5; ++i) {
    int c = tid + i * 256;
    float qv = rintf(vals[i] / sc);
    qv = fminf(fmaxf(qv, -127.f), 127.f);
    q[(size_t)row * E_DIM + c] = (int8_t)qv;
  }
}

// ---------- exact GELU + per-token quant (F=5120, bf16 in, int8 in-place) ----------
__global__ __launch_bounds__(256) void gelu_quant_kernel(
    const __hip_bfloat16* __restrict__ f1, int8_t* __restrict__ q, float* __restrict__ s) {
  __shared__ float red[4];
  const int row = blockIdx.x;
  const int tid = threadIdx.x;
  const __hip_bfloat16* xr = f1 + (size_t)row * F_DIM;
  float g[20]; float amax = 0.f;
#pragma unroll
  for (int i = 0; i < 20; ++i) {
    float v = __bfloat162float(xr[tid + i * 256]);
    float gv = 0.5f * v * (1.0f + erff(v * 0.70710678118654752440f));
    g[i] = gv;
    amax = fmaxf(amax, fabsf(gv));
  }
  amax = wred_max(amax);
  if ((tid & 63) == 0) red[tid >> 6] = amax;
  __syncthreads();
  amax = fmaxf(fmaxf(red[0], red[1]), fmaxf(red[2], red[3]));
  float sc = amax * (1.0f / 127.0f);
  if (tid == 0) s[row] = sc;
  int8_t* qr = q + (size_t)row * (2 * F_DIM);   // strided in-place rows
#pragma unroll
  for (int i = 0; i < 20; ++i) {
    int c = tid + i * 256;
    float qv = rintf(g[i] / sc);
    qv = fminf(fmaxf(qv, -127.f), 127.f);
    qr[c] = (int8_t)qv;
  }
}

// ---------- int8 GEMM (unchanged from passing round) ----------
template <int MODE>
__global__ __launch_bounds__(256) void gemm_i8(
    const int8_t* __restrict__ A, const int8_t* __restrict__ B,
    const float* __restrict__ sx, const float* __restrict__ sw,
    const float* __restrict__ bias, const float* __restrict__ resid,
    void* __restrict__ outp, int M, int N, int K, int lda) {
  __shared__ __align__(16) int8_t Asl[128 * 64];
  __shared__ __align__(16) int8_t Bsl[128 * 64];
  const int tid = threadIdx.x;
  const int lane = tid & 63;
  const int wave = tid >> 6;
  const int wm = wave >> 1, wn = wave & 1;
  const int quad = lane >> 4;
  const int l16 = lane & 15;
  const int m0 = blockIdx.y * 128;
  const int n0 = blockIdx.x * 128;

  v4i acc[4][4];
#pragma unroll
  for (int i = 0; i < 4; ++i)
#pragma unroll
    for (int j = 0; j < 4; ++j) acc[i][j] = (v4i){0, 0, 0, 0};

  const int nk = K >> 6;
#pragma unroll 1
  for (int ks = 0; ks < nk; ++ks) {
    __syncthreads();
    const long k0 = (long)ks * 64;
#pragma unroll
    for (int issue = 0; issue < 2; ++issue) {
      int c = (issue * 4 + wave) * 64 + lane;
      int row = c >> 2;
      int scol = (c & 3) << 4;
      int gcol = scol ^ ((row & 3) << 4);
      gload_lds16(A + (long)(m0 + row) * lda + k0 + gcol, &Asl[c * 16]);
      gload_lds16(B + (long)(n0 + row) * K + k0 + gcol, &Bsl[c * 16]);
    }
    __syncthreads();
    v4i af[4], bf[4];
#pragma unroll
    for (int i = 0; i < 4; ++i) {
      int row = wm * 64 + i * 16 + l16;
      af[i] = *(const v4i*)&Asl[row * 64 + ((quad * 16) ^ ((row & 3) << 4))];
    }
#pragma unroll
    for (int j = 0; j < 4; ++j) {
      int row = wn * 64 + j * 16 + l16;
      bf[j] = *(const v4i*)&Bsl[row * 64 + ((quad * 16) ^ ((row & 3) << 4))];
    }
#pragma unroll
    for (int i = 0; i < 4; ++i)
#pragma unroll
      for (int j = 0; j < 4; ++j)
        acc[i][j] = __builtin_amdgcn_mfma_i32_16x16x64_i8(af[i], bf[j], acc[i][j], 0, 0, 0);
  }

  float swv[4], bv[4];
#pragma unroll
  for (int j = 0; j < 4; ++j) {
    int n = n0 + wn * 64 + j * 16 + l16;
    swv[j] = sw[n];
    bv[j] = bias[n];
  }
#pragma unroll
  for (int i = 0; i < 4; ++i) {
#pragma unroll
    for (int r = 0; r < 4; ++r) {
      int m = m0 + wm * 64 + i * 16 + quad * 4 + r;
      float sxm = sx[m];
#pragma unroll
      for (int j = 0; j < 4; ++j) {
        int n = n0 + wn * 64 + j * 16 + l16;
        float v = (float)acc[i][j][r] * (sxm * swv[j]) + bv[j];
        if constexpr (MODE == 0) {
          ((__hip_bfloat16*)outp)[(size_t)m * N + n] = __float2bfloat16(v);
        } else {
          ((float*)outp)[(size_t)m * N + n] = v + resid[(size_t)m * N + n];
        }
      }
    }
  }
}

// ---------- V transpose: Vt[bh][d][k] = V[b,k,h,d] ----------
__global__ __launch_bounds__(256) void vt_kernel(
    const __hip_bfloat16* __restrict__ qkv, __hip_bfloat16* __restrict__ Vt) {
  __shared__ __hip_bfloat16 tile[64][72];
  const int bh = blockIdx.y, kc = blockIdx.x;
  const int b = bh / NH, h = bh % NH;
  const int tid = threadIdx.x;
  const size_t base = ((size_t)b * S_LEN + (size_t)kc * 64) * (3 * E_DIM) + 2 * E_DIM + h * 64;
#pragma unroll
  for (int i = 0; i < 2; ++i) {
    int idx = tid + i * 256;
    int row = idx >> 3, c8 = (idx & 7) * 8;
    *(uint4*)&tile[row][c8] = *(const uint4*)(qkv + base + (size_t)row * (3 * E_DIM) + c8);
  }
  __syncthreads();
#pragma unroll
  for (int i = 0; i < 2; ++i) {
    int idx = tid + i * 256;
    int d = idx >> 3, k8 = (idx & 7) * 8;
    __hip_bfloat16 v[8] __attribute__((aligned(16)));
#pragma unroll
    for (int j = 0; j < 8; ++j) v[j] = tile[k8 + j][d];
    *(uint4*)&Vt[((size_t)bh * 64 + d) * 1024 + (size_t)kc * 64 + k8] = *(uint4*)v;
  }
}

// ---------- MFMA attention: block = (b,h) x 16 q-rows; exact 2-pass softmax ----------
__global__ __launch_bounds__(256) void attn_mfma_kernel(
    const __hip_bfloat16* __restrict__ qkv, const __hip_bfloat16* __restrict__ Vt,
    __hip_bfloat16* __restrict__ attn) {
  constexpr int E3 = 3 * E_DIM;
  constexpr int PS = 1032;                     // P row stride (bf16), padded
  __shared__ __align__(16) char sm[33536];     // P (33024) aliased by Ored (16384); mred tail (512)
  __hip_bfloat16* P = (__hip_bfloat16*)sm;
  float* Ored = (float*)sm;
  float* mred = (float*)(sm + 33024);

  const int tid = threadIdx.x;
  const int lane = tid & 63;
  const int wave = tid >> 6;
  const int l16 = lane & 15;
  const int quad = lane >> 4;
  const int bh = blockIdx.y;
  const int b = bh / NH, h = bh % NH;
  const int q0 = blockIdx.x * 16;
  const size_t base_t = (size_t)b * S_LEN;

  // Q A-fragments: A[m=l16][k=quad*8+j], 2 k-steps over hd=64
  v8s aq0, aq1;
  {
    const __hip_bfloat16* qp = qkv + (base_t + q0 + l16) * (size_t)E3 + h * 64 + quad * 8;
    aq0 = *(const v8s*)qp;
    aq1 = *(const v8s*)(qp + 32);
  }

  // ---- scores: wave w covers k-cols [w*256, w*256+256) : 16 tiles ----
  v4f accs[16];
  {
    const __hip_bfloat16* kp =
        qkv + (base_t + wave * 256 + l16) * (size_t)E3 + E_DIM + h * 64 + quad * 8;
#pragma unroll
    for (int nt = 0; nt < 16; ++nt) {
      const __hip_bfloat16* kr = kp + (size_t)nt * 16 * E3;
      v8s b0 = *(const v8s*)kr;
      v8s b1 = *(const v8s*)(kr + 32);
      v4f z = {0.f, 0.f, 0.f, 0.f};
      z = __builtin_amdgcn_mfma_f32_16x16x32_bf16(aq0, b0, z, 0, 0, 0);
      accs[nt] = __builtin_amdgcn_mfma_f32_16x16x32_bf16(aq1, b1, z, 0, 0, 0);
    }
  }

  // ---- softmax (raw scores; 0.125 scale folded into exp arg) ----
  float mx[4];
#pragma unroll
  for (int r = 0; r < 4; ++r) {
    float m = -3.0e38f;
#pragma unroll
    for (int nt = 0; nt < 16; ++nt) m = fmaxf(m, accs[nt][r]);
#pragma unroll
    for (int off = 1; off < 16; off <<= 1) m = fmaxf(m, __shfl_xor(m, off, 64));
    mx[r] = m;
  }
  if (l16 == 0) {
#pragma unroll
    for (int r = 0; r < 4; ++r) mred[wave * 16 + quad * 4 + r] = mx[r];
  }
  __syncthreads();
#pragma unroll
  for (int r = 0; r < 4; ++r) {
    int row = quad * 4 + r;
    mx[r] = fmaxf(fmaxf(mred[row], mred[16 + row]), fmaxf(mred[32 + row], mred[48 + row]));
  }
  float ls[4] = {0.f, 0.f, 0.f, 0.f};
#pragma unroll
  for (int nt = 0; nt < 16; ++nt) {
#pragma unroll
    for (int r = 0; r < 4; ++r) {
      float e = __expf(0.125f * (accs[nt][r] - mx[r]));
      accs[nt][r] = e;
      ls[r] += e;
    }
  }
#pragma unroll
  for (int r = 0; r < 4; ++r) {
#pragma unroll
    for (int off = 1; off < 16; off <<= 1) ls[r] += __shfl_xor(ls[r], off, 64);
  }
  if (l16 == 0) {
#pragma unroll
    for (int r = 0; r < 4; ++r) mred[64 + wave * 16 + quad * 4 + r] = ls[r];
  }
  __syncthreads();
  float inv[4];
#pragma unroll
  for (int r = 0; r < 4; ++r) {
    int row = quad * 4 + r;
    inv[r] = 1.0f / (mred[64 + row] + mred[80 + row] + mred[96 + row] + mred[112 + row]);
  }
  // write P (bf16) in C-layout positions
#pragma unroll
  for (int nt = 0; nt < 16; ++nt) {
    int col = wave * 256 + nt * 16 + l16;
#pragma unroll
    for (int r = 0; r < 4; ++r)
      P[(quad * 4 + r) * PS + col] = __float2bfloat16(accs[nt][r] * inv[r]);
  }
  __syncthreads();

  // ---- PV: O[16][64]; wave w reduces its k-range; A=P(LDS), B=Vt(global) ----
  v4f oc[4];
#pragma unroll
  for (int dt = 0; dt < 4; ++dt) oc[dt] = (v4f){0.f, 0.f, 0.f, 0.f};
  {
    const __hip_bfloat16* vtb = Vt + ((size_t)bh * 64 + l16) * 1024 + wave * 256 + quad * 8;
    const __hip_bfloat16* pb = P + l16 * PS + wave * 256 + quad * 8;
#pragma unroll
    for (int ks = 0; ks < 8; ++ks) {
      v8s ap = *(const v8s*)(pb + ks * 32);
#pragma unroll
      for (int dt = 0; dt < 4; ++dt) {
        v8s bv = *(const v8s*)(vtb + (size_t)dt * 16 * 1024 + ks * 32);
        oc[dt] = __builtin_amdgcn_mfma_f32_16x16x32_bf16(ap, bv, oc[dt], 0, 0, 0);
      }
    }
  }
  __syncthreads();   // all P reads done before Ored overwrites the region
#pragma unroll
  for (int dt = 0; dt < 4; ++dt)
#pragma unroll
    for (int r = 0; r < 4; ++r)
      Ored[wave * 1024 + (quad * 4 + r) * 64 + dt * 16 + l16] = oc[dt][r];
  __syncthreads();
  {
    int row = tid >> 4, d0 = (tid & 15) * 4;
    float o[4] = {0.f, 0.f, 0.f, 0.f};
#pragma unroll
    for (int w = 0; w < 4; ++w) {
      const float* src = &Ored[w * 1024 + row * 64 + d0];
#pragma unroll
      for (int u = 0; u < 4; ++u) o[u] += src[u];
    }
    __hip_bfloat16 ob[4] __attribute__((aligned(8)));
#pragma unroll
    for (int u = 0; u < 4; ++u) ob[u] = __float2bfloat16(o[u]);
    *(uint2*)(attn + (base_t + q0 + row) * (size_t)E_DIM + h * 64 + d0) = *(uint2*)ob;
  }
}

// ---------- launch ----------
extern "C" void kernel_launch(void* const* d_in, const int* in_sizes, int n_in,
                              void* d_out, int out_size, void* d_ws, size_t ws_size,
                              hipStream_t stream) {
  const float* hidden = (const float*)d_in[0];
  const float* ln1_w = (const float*)d_in[1];
  const float* ln1_b = (const float*)d_in[2];
  const float* ln2_w = (const float*)d_in[3];
  const float* ln2_b = (const float*)d_in[4];
  const float* W_qkv = (const float*)d_in[5];
  const float* b_qkv = (const float*)d_in[6];
  const float* W_out = (const float*)d_in[7];
  const float* b_out = (const float*)d_in[8];
  const float* W_fc1 = (const float*)d_in[9];
  const float* b_fc1 = (const float*)d_in[10];
  const float* W_fc2 = (const float*)d_in[11];
  const float* b_fc2 = (const float*)d_in[12];

  // ---- workspace plan (~250.7 MB) ----
  char* ws = (char*)d_ws;
  size_t off = 0;
  auto alloc = [&](size_t bytes) {
    void* p = ws + off;
    off += (bytes + 255) & ~(size_t)255;
    return p;
  };
  int8_t* qw_qkv = (int8_t*)alloc((size_t)3 * E_DIM * E_DIM);
  int8_t* qw_out = (int8_t*)alloc((size_t)E_DIM * E_DIM);
  int8_t* qw_fc1 = (int8_t*)alloc((size_t)F_DIM * E_DIM);
  int8_t* qw_fc2 = (int8_t*)alloc((size_t)E_DIM * F_DIM);
  float* sw_qkv = (float*)alloc((size_t)3 * E_DIM * 4);
  float* sw_out = (float*)alloc((size_t)E_DIM * 4);
  float* sw_fc1 = (float*)alloc((size_t)F_DIM * 4);
  float* sw_fc2 = (float*)alloc((size_t)E_DIM * 4);
  float* sx1 = (float*)alloc((size_t)T_DIM * 4);
  float* sa  = (float*)alloc((size_t)T_DIM * 4);
  float* sx2 = (float*)alloc((size_t)T_DIM * 4);
  float* sg  = (float*)alloc((size_t)T_DIM * 4);
  int8_t* qx = (int8_t*)alloc((size_t)T_DIM * E_DIM);              // reused 3x
  char* R = (char*)alloc((size_t)T_DIM * 3 * E_DIM * 2 +           // 209,715,200 B
                         (size_t)T_DIM * E_DIM * 4);
  // phase A: qkv(126MB) | attn bf16(42MB) | Vt(42MB)  == exactly 210MB
  __hip_bfloat16* qkv_bf = (__hip_bfloat16*)R;
  __hip_bfloat16* attn_bf = (__hip_bfloat16*)(R + (size_t)T_DIM * 3 * E_DIM * 2);
  __hip_bfloat16* Vt = (__hip_bfloat16*)(R + (size_t)T_DIM * 3 * E_DIM * 2 +
                                         (size_t)T_DIM * E_DIM * 2);
  // phase B aliases (phase-A buffers dead)
  __hip_bfloat16* f1_bf = (__hip_bfloat16*)R;
  int8_t* qg = (int8_t*)R;                                         // strided lda=2F
  float* hidden2 = (float*)d_out;

  // 1) weight quantization
  wquant_kernel<<<3 * E_DIM, 256, 0, stream>>>(W_qkv, qw_qkv, sw_qkv, E_DIM);
  wquant_kernel<<<E_DIM, 256, 0, stream>>>(W_out, qw_out, sw_out, E_DIM);
  wquant_kernel<<<F_DIM, 256, 0, stream>>>(W_fc1, qw_fc1, sw_fc1, E_DIM);
  wquant_kernel<<<E_DIM, 256, 0, stream>>>(W_fc2, qw_fc2, sw_fc2, F_DIM);
  // 2) rms1 + quant
  rms_quant_kernel<<<T_DIM, 256, 0, stream>>>(hidden, ln1_w, ln1_b, qx, sx1);
  // 3) QKV gemm -> bf16
  gemm_i8<0><<<dim3(3 * E_DIM / 128, T_DIM / 128), 256, 0, stream>>>(
      qx, qw_qkv, sx1, sw_qkv, b_qkv, nullptr, qkv_bf, T_DIM, 3 * E_DIM, E_DIM, E_DIM);
  // 4) V transpose
  vt_kernel<<<dim3(S_LEN / 64, B_SZ * NH), 256, 0, stream>>>(qkv_bf, Vt);
  // 5) MFMA attention -> bf16
  attn_mfma_kernel<<<dim3(S_LEN / 16, B_SZ * NH), 256, 0, stream>>>(qkv_bf, Vt, attn_bf);
  // 6) quant attn
  row_quant_bf_kernel<<<T_DIM, 256, 0, stream>>>(attn_bf, qx, sa);
  // 7) out proj + residual -> hidden2 (= d_out)
  gemm_i8<1><<<dim3(E_DIM / 128, T_DIM / 128), 256, 0, stream>>>(
      qx, qw_out, sa, sw_out, b_out, hidden, hidden2, T_DIM, E_DIM, E_DIM, E_DIM);
  // 8) rms2 + quant
  rms_quant_kernel<<<T_DIM, 256, 0, stream>>>(hidden2, ln2_w, ln2_b, qx, sx2);
  // 9) FC1 gemm -> bf16 (R region free again)
  gemm_i8<0><<<dim3(F_DIM / 128, T_DIM / 128), 256, 0, stream>>>(
      qx, qw_fc1, sx2, sw_fc1, b_fc1, nullptr, f1_bf, T_DIM, F_DIM, E_DIM, E_DIM);
  // 10) gelu + quant (in-place strided int8 rows inside f1 buffer)
  gelu_quant_kernel<<<T_DIM, 256, 0, stream>>>(f1_bf, qg, sg);
  // 11) FC2 gemm + residual -> d_out (in-place, element-private)
  gemm_i8<1><<<dim3(E_DIM / 128, T_DIM / 128), 256, 0, stream>>>(
      qg, qw_fc2, sg, sw_fc2, b_fc2, hidden2, (float*)d_out, T_DIM, E_DIM, F_DIM, 2 * F_DIM);
}

// Round 4
// 1148.562 us; speedup vs baseline: 2.9568x; 1.3844x over previous
//
#include <hip/hip_runtime.h>
#include <hip/hip_bf16.h>
#include <stdint.h>

#define E_DIM 1280
#define F_DIM 5120
#define T_DIM 16384
#define B_SZ  16
#define S_LEN 1024
#define NH    20

typedef int v4i __attribute__((ext_vector_type(4)));
typedef __attribute__((ext_vector_type(8))) short v8s;
typedef __attribute__((ext_vector_type(4))) float v4f;

// ---------- helpers ----------
__device__ __forceinline__ float wred_sum(float v) {
#pragma unroll
  for (int m = 32; m > 0; m >>= 1) v += __shfl_xor(v, m, 64);
  return v;
}
__device__ __forceinline__ float wred_max(float v) {
#pragma unroll
  for (int m = 32; m > 0; m >>= 1) v = fmaxf(v, __shfl_xor(v, m, 64));
  return v;
}
__device__ __forceinline__ void gload_lds16(const void* g, void* l) {
  __builtin_amdgcn_global_load_lds((const __attribute__((address_space(1))) void*)g,
                                   (__attribute__((address_space(3))) void*)l, 16, 0, 0);
}

// ---------- per-output-channel weight quant ----------
__global__ __launch_bounds__(256) void wquant_kernel(
    const float* __restrict__ W, int8_t* __restrict__ qw, float* __restrict__ sw, int K) {
  __shared__ float red[4];
  const int row = blockIdx.x;
  const int tid = threadIdx.x;
  const float* wr = W + (size_t)row * K;
  float amax = 0.f;
  for (int c = tid; c < K; c += 256) amax = fmaxf(amax, fabsf(wr[c]));
  amax = wred_max(amax);
  if ((tid & 63) == 0) red[tid >> 6] = amax;
  __syncthreads();
  amax = fmaxf(fmaxf(red[0], red[1]), fmaxf(red[2], red[3]));
  float sc = amax * (1.0f / 127.0f);
  if (tid == 0) sw[row] = sc;
  for (int c = tid; c < K; c += 256) {
    float qv = rintf(wr[c] / sc);
    qw[(size_t)row * K + c] = (int8_t)qv;
  }
}

// ---------- RMSNorm(+bias) + per-token quant (E=1280) ----------
__global__ __launch_bounds__(256) void rms_quant_kernel(
    const float* __restrict__ x, const float* __restrict__ w, const float* __restrict__ b,
    int8_t* __restrict__ q, float* __restrict__ s) {
  __shared__ float red[4];
  const int row = blockIdx.x;
  const int tid = threadIdx.x;
  const float* xr = x + (size_t)row * E_DIM;
  float vals[5];
  float ss = 0.f;
#pragma unroll
  for (int i = 0; i < 5; ++i) {
    float v = xr[tid + i * 256];
    vals[i] = v; ss += v * v;
  }
  ss = wred_sum(ss);
  if ((tid & 63) == 0) red[tid >> 6] = ss;
  __syncthreads();
  ss = red[0] + red[1] + red[2] + red[3];
  float rstd = rsqrtf(ss * (1.0f / E_DIM) + 1e-6f);
  float y[5]; float amax = 0.f;
#pragma unroll
  for (int i = 0; i < 5; ++i) {
    int c = tid + i * 256;
    float v = vals[i] * rstd * w[c] + b[c];
    y[i] = v;
    amax = fmaxf(amax, fabsf(v));
  }
  amax = wred_max(amax);
  __syncthreads();
  if ((tid & 63) == 0) red[tid >> 6] = amax;
  __syncthreads();
  amax = fmaxf(fmaxf(red[0], red[1]), fmaxf(red[2], red[3]));
  float sc = amax * (1.0f / 127.0f);
  if (tid == 0) s[row] = sc;
#pragma unroll
  for (int i = 0; i < 5; ++i) {
    int c = tid + i * 256;
    float qv = rintf(y[i] / sc);
    qv = fminf(fmaxf(qv, -127.f), 127.f);
    q[(size_t)row * E_DIM + c] = (int8_t)qv;
  }
}

// ---------- per-token quant (E=1280, bf16 in) ----------
__global__ __launch_bounds__(256) void row_quant_bf_kernel(
    const __hip_bfloat16* __restrict__ x, int8_t* __restrict__ q, float* __restrict__ s) {
  __shared__ float red[4];
  const int row = blockIdx.x;
  const int tid = threadIdx.x;
  const __hip_bfloat16* xr = x + (size_t)row * E_DIM;
  float vals[5]; float amax = 0.f;
#pragma unroll
  for (int i = 0; i < 5; ++i) {
    float v = __bfloat162float(xr[tid + i * 256]);
    vals[i] = v;
    amax = fmaxf(amax, fabsf(v));
  }
  amax = wred_max(amax);
  if ((tid & 63) == 0) red[tid >> 6] = amax;
  __syncthreads();
  amax = fmaxf(fmaxf(red[0], red[1]), fmaxf(red[2], red[3]));
  float sc = amax * (1.0f / 127.0f);
  if (tid == 0) s[row] = sc;
#pragma unroll
  for (int i = 0; i < 5; ++i) {
    int c = tid + i * 256;
    float qv = rintf(vals[i] / sc);
    qv = fminf(fmaxf(qv, -127.f), 127.f);
    q[(size_t)row * E_DIM + c] = (int8_t)qv;
  }
}

// ---------- exact GELU + per-token quant (F=5120, bf16 in, int8 in-place) ----------
__global__ __launch_bounds__(256) void gelu_quant_kernel(
    const __hip_bfloat16* __restrict__ f1, int8_t* __restrict__ q, float* __restrict__ s) {
  __shared__ float red[4];
  const int row = blockIdx.x;
  const int tid = threadIdx.x;
  const __hip_bfloat16* xr = f1 + (size_t)row * F_DIM;
  float g[20]; float amax = 0.f;
#pragma unroll
  for (int i = 0; i < 20; ++i) {
    float v = __bfloat162float(xr[tid + i * 256]);
    float gv = 0.5f * v * (1.0f + erff(v * 0.70710678118654752440f));
    g[i] = gv;
    amax = fmaxf(amax, fabsf(gv));
  }
  amax = wred_max(amax);
  if ((tid & 63) == 0) red[tid >> 6] = amax;
  __syncthreads();
  amax = fmaxf(fmaxf(red[0], red[1]), fmaxf(red[2], red[3]));
  float sc = amax * (1.0f / 127.0f);
  if (tid == 0) s[row] = sc;
  int8_t* qr = q + (size_t)row * (2 * F_DIM);   // strided in-place rows
#pragma unroll
  for (int i = 0; i < 20; ++i) {
    int c = tid + i * 256;
    float qv = rintf(g[i] / sc);
    qv = fminf(fmaxf(qv, -127.f), 127.f);
    qr[c] = (int8_t)qv;
  }
}

// ---------- int8 GEMM (unchanged from passing round) ----------
template <int MODE>
__global__ __launch_bounds__(256) void gemm_i8(
    const int8_t* __restrict__ A, const int8_t* __restrict__ B,
    const float* __restrict__ sx, const float* __restrict__ sw,
    const float* __restrict__ bias, const float* __restrict__ resid,
    void* __restrict__ outp, int M, int N, int K, int lda) {
  __shared__ __align__(16) int8_t Asl[128 * 64];
  __shared__ __align__(16) int8_t Bsl[128 * 64];
  const int tid = threadIdx.x;
  const int lane = tid & 63;
  const int wave = tid >> 6;
  const int wm = wave >> 1, wn = wave & 1;
  const int quad = lane >> 4;
  const int l16 = lane & 15;
  const int m0 = blockIdx.y * 128;
  const int n0 = blockIdx.x * 128;

  v4i acc[4][4];
#pragma unroll
  for (int i = 0; i < 4; ++i)
#pragma unroll
    for (int j = 0; j < 4; ++j) acc[i][j] = (v4i){0, 0, 0, 0};

  const int nk = K >> 6;
#pragma unroll 1
  for (int ks = 0; ks < nk; ++ks) {
    __syncthreads();
    const long k0 = (long)ks * 64;
#pragma unroll
    for (int issue = 0; issue < 2; ++issue) {
      int c = (issue * 4 + wave) * 64 + lane;
      int row = c >> 2;
      int scol = (c & 3) << 4;
      int gcol = scol ^ ((row & 3) << 4);
      gload_lds16(A + (long)(m0 + row) * lda + k0 + gcol, &Asl[c * 16]);
      gload_lds16(B + (long)(n0 + row) * K + k0 + gcol, &Bsl[c * 16]);
    }
    __syncthreads();
    v4i af[4], bf[4];
#pragma unroll
    for (int i = 0; i < 4; ++i) {
      int row = wm * 64 + i * 16 + l16;
      af[i] = *(const v4i*)&Asl[row * 64 + ((quad * 16) ^ ((row & 3) << 4))];
    }
#pragma unroll
    for (int j = 0; j < 4; ++j) {
      int row = wn * 64 + j * 16 + l16;
      bf[j] = *(const v4i*)&Bsl[row * 64 + ((quad * 16) ^ ((row & 3) << 4))];
    }
#pragma unroll
    for (int i = 0; i < 4; ++i)
#pragma unroll
      for (int j = 0; j < 4; ++j)
        acc[i][j] = __builtin_amdgcn_mfma_i32_16x16x64_i8(af[i], bf[j], acc[i][j], 0, 0, 0);
  }

  float swv[4], bv[4];
#pragma unroll
  for (int j = 0; j < 4; ++j) {
    int n = n0 + wn * 64 + j * 16 + l16;
    swv[j] = sw[n];
    bv[j] = bias[n];
  }
#pragma unroll
  for (int i = 0; i < 4; ++i) {
#pragma unroll
    for (int r = 0; r < 4; ++r) {
      int m = m0 + wm * 64 + i * 16 + quad * 4 + r;
      float sxm = sx[m];
#pragma unroll
      for (int j = 0; j < 4; ++j) {
        int n = n0 + wn * 64 + j * 16 + l16;
        float v = (float)acc[i][j][r] * (sxm * swv[j]) + bv[j];
        if constexpr (MODE == 0) {
          ((__hip_bfloat16*)outp)[(size_t)m * N + n] = __float2bfloat16(v);
        } else {
          ((float*)outp)[(size_t)m * N + n] = v + resid[(size_t)m * N + n];
        }
      }
    }
  }
}

// ---------- V transpose: Vt[bh][d][k] = V[b,k,h,d] ----------
__global__ __launch_bounds__(256) void vt_kernel(
    const __hip_bfloat16* __restrict__ qkv, __hip_bfloat16* __restrict__ Vt) {
  __shared__ __hip_bfloat16 tile[64][72];
  const int bh = blockIdx.y, kc = blockIdx.x;
  const int b = bh / NH, h = bh % NH;
  const int tid = threadIdx.x;
  const size_t base = ((size_t)b * S_LEN + (size_t)kc * 64) * (3 * E_DIM) + 2 * E_DIM + h * 64;
#pragma unroll
  for (int i = 0; i < 2; ++i) {
    int idx = tid + i * 256;
    int row = idx >> 3, c8 = (idx & 7) * 8;
    *(uint4*)&tile[row][c8] = *(const uint4*)(qkv + base + (size_t)row * (3 * E_DIM) + c8);
  }
  __syncthreads();
#pragma unroll
  for (int i = 0; i < 2; ++i) {
    int idx = tid + i * 256;
    int d = idx >> 3, k8 = (idx & 7) * 8;
    __hip_bfloat16 v[8] __attribute__((aligned(16)));
#pragma unroll
    for (int j = 0; j < 8; ++j) v[j] = tile[k8 + j][d];
    *(uint4*)&Vt[((size_t)bh * 64 + d) * 1024 + (size_t)kc * 64 + k8] = *(uint4*)v;
  }
}

// ---------- flash MFMA attention ----------
// Block = (b,h) x 64 q-rows; 4 waves, wave owns 16 q-rows over full k.
// K/V staged per 128-k tile into LDS (XOR chunk swizzle); online softmax.
// Scores computed TRANSPOSED (A=K-frag, B=Q-frag) so each lane's 4 C-regs are
// contiguous k for one q -> P spills to LDS as ds_write_b64.
__global__ __launch_bounds__(256) void attn_flash_kernel(
    const __hip_bfloat16* __restrict__ qkv, const __hip_bfloat16* __restrict__ Vt,
    __hip_bfloat16* __restrict__ attn) {
  constexpr int E3 = 3 * E_DIM;
  __shared__ __align__(16) __hip_bfloat16 Ks[128 * 64];   // [row][8 chunks, ^(row&7)]
  __shared__ __align__(16) __hip_bfloat16 Vs[64 * 128];   // [d][16 chunks, ^(d&15)]
  __shared__ __align__(16) __hip_bfloat16 Ps[4][16 * 128];// per wave [q][16 ch, ^(q)]
  __shared__ float stats[4][16];

  const int tid = threadIdx.x;
  const int lane = tid & 63;
  const int wave = tid >> 6;
  const int l16 = lane & 15;
  const int quad = lane >> 4;
  const int bh = blockIdx.y;
  const int b = bh / NH, h = bh % NH;
  const int q0 = blockIdx.x * 64;
  const size_t base_t = (size_t)b * S_LEN;

  // Q B-fragments for this wave's 16 q-rows (B[n=q][k=d])
  v8s qb0, qb1;
  {
    const __hip_bfloat16* qp =
        qkv + (base_t + q0 + wave * 16 + l16) * (size_t)E3 + h * 64 + quad * 8;
    qb0 = *(const v8s*)qp;
    qb1 = *(const v8s*)(qp + 32);
  }

  float m_prev = -3.0e38f;
  float lsum = 0.f;
  v4f oc[4];
#pragma unroll
  for (int dt = 0; dt < 4; ++dt) oc[dt] = (v4f){0.f, 0.f, 0.f, 0.f};

  const __hip_bfloat16* kgbase = qkv + base_t * E3 + E_DIM + h * 64;
  const __hip_bfloat16* vgbase = Vt + (size_t)bh * 64 * 1024;
  __hip_bfloat16* pw = Ps[wave];

#pragma unroll 1
  for (int t = 0; t < 8; ++t) {
    __syncthreads();  // all waves done reading previous Ks/Vs tile
#pragma unroll
    for (int i = 0; i < 4; ++i) {   // stage K tile: 128 rows x 128B
      int c = tid + i * 256;
      int row = c >> 3, lc = c & 7;
      int gc = lc ^ (row & 7);
      gload_lds16(kgbase + (size_t)(t * 128 + row) * E3 + gc * 8, (char*)Ks + c * 16);
    }
#pragma unroll
    for (int i = 0; i < 4; ++i) {   // stage V tile: 64 d x 256B
      int c = tid + i * 256;
      int d = c >> 4, lc = c & 15;
      int gc = lc ^ (d & 15);
      gload_lds16(vgbase + (size_t)d * 1024 + t * 128 + gc * 8, (char*)Vs + c * 16);
    }
    __syncthreads();  // staged (vmcnt drained by barrier semantics)

    // ---- scores^T: D[kc][q] ; 8 kc-tiles of 16 ----
    v4f accT[8];
#pragma unroll
    for (int nt = 0; nt < 8; ++nt) {
      int row = nt * 16 + l16;
      const char* kr = (const char*)Ks + row * 128;
      v8s ak0 = *(const v8s*)(kr + ((quad ^ (row & 7)) * 16));
      v8s ak1 = *(const v8s*)(kr + (((quad + 4) ^ (row & 7)) * 16));
      v4f z = {0.f, 0.f, 0.f, 0.f};
      z = __builtin_amdgcn_mfma_f32_16x16x32_bf16(ak0, qb0, z, 0, 0, 0);
      accT[nt] = __builtin_amdgcn_mfma_f32_16x16x32_bf16(ak1, qb1, accT[nt] = z, 0, 0, 0);
    }

    // ---- online softmax (per-lane q = l16; quads hold disjoint k-slices) ----
    float mt = -3.0e38f;
#pragma unroll
    for (int nt = 0; nt < 8; ++nt)
#pragma unroll
      for (int r = 0; r < 4; ++r) mt = fmaxf(mt, accT[nt][r]);
    mt = fmaxf(mt, __shfl_xor(mt, 16, 64));
    mt = fmaxf(mt, __shfl_xor(mt, 32, 64));
    float m_new = fmaxf(m_prev, mt);
    float alpha = __expf(0.125f * (m_prev - m_new));
    m_prev = m_new;
    float ts = 0.f;
#pragma unroll
    for (int nt = 0; nt < 8; ++nt)
#pragma unroll
      for (int r = 0; r < 4; ++r) {
        float e = __expf(0.125f * (accT[nt][r] - m_new));
        accT[nt][r] = e;
        ts += e;
      }
    lsum = lsum * alpha + ts;
    if (quad == 0) stats[wave][l16] = alpha;
    // write P rows (q=l16): 4 contiguous k per reg-group -> b64
#pragma unroll
    for (int nt = 0; nt < 8; ++nt) {
      __hip_bfloat16 pk[4] __attribute__((aligned(8)));
#pragma unroll
      for (int r = 0; r < 4; ++r) pk[r] = __float2bfloat16(accT[nt][r]);
      int lcq = 2 * nt + (quad >> 1);
      *(uint2*)((char*)pw + l16 * 256 + ((lcq ^ l16) * 16) + (quad & 1) * 8) = *(uint2*)pk;
    }
    // rescale O (alpha for q=quad*4+r via LDS; same-wave DS ops are in-order)
    v4f a4 = *(v4f*)&stats[wave][quad * 4];
#pragma unroll
    for (int dt = 0; dt < 4; ++dt)
#pragma unroll
      for (int r = 0; r < 4; ++r) oc[dt][r] *= a4[r];
    // ---- PV: A=P[q][k], B=Vs[d][k] ----
#pragma unroll
    for (int ks = 0; ks < 4; ++ks) {
      int pch = (ks * 4 + quad) ^ l16;
      v8s ap = *(const v8s*)((char*)pw + l16 * 256 + pch * 16);
#pragma unroll
      for (int dt = 0; dt < 4; ++dt) {
        int d = dt * 16 + l16;
        v8s bv = *(const v8s*)((char*)Vs + d * 256 + (((ks * 4 + quad) ^ l16) * 16));
        oc[dt] = __builtin_amdgcn_mfma_f32_16x16x32_bf16(ap, bv, oc[dt], 0, 0, 0);
      }
    }
  }

  // ---- epilogue: finish l, normalize, store ----
  lsum += __shfl_xor(lsum, 16, 64);
  lsum += __shfl_xor(lsum, 32, 64);
  if (quad == 0) stats[wave][l16] = lsum;
  v4f l4 = *(v4f*)&stats[wave][quad * 4];
  float inv[4];
#pragma unroll
  for (int r = 0; r < 4; ++r) inv[r] = 1.0f / l4[r];
#pragma unroll
  for (int dt = 0; dt < 4; ++dt)
#pragma unroll
    for (int r = 0; r < 4; ++r) {
      int tok = q0 + wave * 16 + quad * 4 + r;
      attn[(base_t + tok) * (size_t)E_DIM + h * 64 + dt * 16 + l16] =
          __float2bfloat16(oc[dt][r] * inv[r]);
    }
}

// ---------- launch ----------
extern "C" void kernel_launch(void* const* d_in, const int* in_sizes, int n_in,
                              void* d_out, int out_size, void* d_ws, size_t ws_size,
                              hipStream_t stream) {
  const float* hidden = (const float*)d_in[0];
  const float* ln1_w = (const float*)d_in[1];
  const float* ln1_b = (const float*)d_in[2];
  const float* ln2_w = (const float*)d_in[3];
  const float* ln2_b = (const float*)d_in[4];
  const float* W_qkv = (const float*)d_in[5];
  const float* b_qkv = (const float*)d_in[6];
  const float* W_out = (const float*)d_in[7];
  const float* b_out = (const float*)d_in[8];
  const float* W_fc1 = (const float*)d_in[9];
  const float* b_fc1 = (const float*)d_in[10];
  const float* W_fc2 = (const float*)d_in[11];
  const float* b_fc2 = (const float*)d_in[12];

  // ---- workspace plan (~250.7 MB) ----
  char* ws = (char*)d_ws;
  size_t off = 0;
  auto alloc = [&](size_t bytes) {
    void* p = ws + off;
    off += (bytes + 255) & ~(size_t)255;
    return p;
  };
  int8_t* qw_qkv = (int8_t*)alloc((size_t)3 * E_DIM * E_DIM);
  int8_t* qw_out = (int8_t*)alloc((size_t)E_DIM * E_DIM);
  int8_t* qw_fc1 = (int8_t*)alloc((size_t)F_DIM * E_DIM);
  int8_t* qw_fc2 = (int8_t*)alloc((size_t)E_DIM * F_DIM);
  float* sw_qkv = (float*)alloc((size_t)3 * E_DIM * 4);
  float* sw_out = (float*)alloc((size_t)E_DIM * 4);
  float* sw_fc1 = (float*)alloc((size_t)F_DIM * 4);
  float* sw_fc2 = (float*)alloc((size_t)E_DIM * 4);
  float* sx1 = (float*)alloc((size_t)T_DIM * 4);
  float* sa  = (float*)alloc((size_t)T_DIM * 4);
  float* sx2 = (float*)alloc((size_t)T_DIM * 4);
  float* sg  = (float*)alloc((size_t)T_DIM * 4);
  int8_t* qx = (int8_t*)alloc((size_t)T_DIM * E_DIM);              // reused 3x
  char* R = (char*)alloc((size_t)T_DIM * 3 * E_DIM * 2 +           // 209,715,200 B
                         (size_t)T_DIM * E_DIM * 4);
  // phase A: qkv(126MB) | attn bf16(42MB) | Vt(42MB)  == exactly 210MB
  __hip_bfloat16* qkv_bf = (__hip_bfloat16*)R;
  __hip_bfloat16* attn_bf = (__hip_bfloat16*)(R + (size_t)T_DIM * 3 * E_DIM * 2);
  __hip_bfloat16* Vt = (__hip_bfloat16*)(R + (size_t)T_DIM * 3 * E_DIM * 2 +
                                         (size_t)T_DIM * E_DIM * 2);
  // phase B aliases (phase-A buffers dead)
  __hip_bfloat16* f1_bf = (__hip_bfloat16*)R;
  int8_t* qg = (int8_t*)R;                                         // strided lda=2F
  float* hidden2 = (float*)d_out;

  // 1) weight quantization
  wquant_kernel<<<3 * E_DIM, 256, 0, stream>>>(W_qkv, qw_qkv, sw_qkv, E_DIM);
  wquant_kernel<<<E_DIM, 256, 0, stream>>>(W_out, qw_out, sw_out, E_DIM);
  wquant_kernel<<<F_DIM, 256, 0, stream>>>(W_fc1, qw_fc1, sw_fc1, E_DIM);
  wquant_kernel<<<E_DIM, 256, 0, stream>>>(W_fc2, qw_fc2, sw_fc2, F_DIM);
  // 2) rms1 + quant
  rms_quant_kernel<<<T_DIM, 256, 0, stream>>>(hidden, ln1_w, ln1_b, qx, sx1);
  // 3) QKV gemm -> bf16
  gemm_i8<0><<<dim3(3 * E_DIM / 128, T_DIM / 128), 256, 0, stream>>>(
      qx, qw_qkv, sx1, sw_qkv, b_qkv, nullptr, qkv_bf, T_DIM, 3 * E_DIM, E_DIM, E_DIM);
  // 4) V transpose
  vt_kernel<<<dim3(S_LEN / 64, B_SZ * NH), 256, 0, stream>>>(qkv_bf, Vt);
  // 5) flash MFMA attention -> bf16
  attn_flash_kernel<<<dim3(S_LEN / 64, B_SZ * NH), 256, 0, stream>>>(qkv_bf, Vt, attn_bf);
  // 6) quant attn
  row_quant_bf_kernel<<<T_DIM, 256, 0, stream>>>(attn_bf, qx, sa);
  // 7) out proj + residual -> hidden2 (= d_out)
  gemm_i8<1><<<dim3(E_DIM / 128, T_DIM / 128), 256, 0, stream>>>(
      qx, qw_out, sa, sw_out, b_out, hidden, hidden2, T_DIM, E_DIM, E_DIM, E_DIM);
  // 8) rms2 + quant
  rms_quant_kernel<<<T_DIM, 256, 0, stream>>>(hidden2, ln2_w, ln2_b, qx, sx2);
  // 9) FC1 gemm -> bf16 (R region free again)
  gemm_i8<0><<<dim3(F_DIM / 128, T_DIM / 128), 256, 0, stream>>>(
      qx, qw_fc1, sx2, sw_fc1, b_fc1, nullptr, f1_bf, T_DIM, F_DIM, E_DIM, E_DIM);
  // 10) gelu + quant (in-place strided int8 rows inside f1 buffer)
  gelu_quant_kernel<<<T_DIM, 256, 0, stream>>>(f1_bf, qg, sg);
  // 11) FC2 gemm + residual -> d_out (in-place, element-private)
  gemm_i8<1><<<dim3(E_DIM / 128, T_DIM / 128), 256, 0, stream>>>(
      qg, qw_fc2, sg, sw_fc2, b_fc2, hidden2, (float*)d_out, T_DIM, E_DIM, F_DIM, 2 * F_DIM);
}